// Round 16
// baseline (1406.055 us; speedup 1.0000x reference)
//
#include <hip/hip_runtime.h>
#include <hip/hip_bf16.h>
#include <cstdint>

#define H 128
#define NNODES 20000
#define NEDGES 640000
#define TILE 64
#define PQ_BLOCKS 313
#define EDGE_BLOCKS (NEDGES / TILE)
#define NODE_TILES 625

typedef unsigned short ushort_t;
typedef __attribute__((ext_vector_type(8))) short short8;
typedef __attribute__((ext_vector_type(4))) float floatx4;
typedef __attribute__((ext_vector_type(2))) float floatx2;

__device__ __forceinline__ ushort_t f2bf(float f){
  uint32_t u = __builtin_bit_cast(uint32_t, f);
  u += 0x7fffu + ((u >> 16) & 1u);           // RNE
  return (ushort_t)(u >> 16);
}
// packed RNE fp32x2 -> bf16x2 (v_cvt_pk_bf16_f32 on gfx950)
__device__ __forceinline__ uint32_t pk2bf(float lo, float hi){
  __hip_bfloat162 h2 = __float22bfloat162_rn(make_float2(lo, hi));
  uint32_t u;
  __builtin_memcpy(&u, &h2, 4);
  return u;
}
// unpack bf16x2 dword -> packed float2
__device__ __forceinline__ floatx2 bfpair2(uint32_t u){
  floatx2 r;
  r.x = __builtin_bit_cast(float, u << 16);
  r.y = __builtin_bit_cast(float, u & 0xffff0000u);
  return r;
}
// fast silu: v_exp_f32 + v_rcp_f32
__device__ __forceinline__ float silu_f(float x){
  float e = __builtin_amdgcn_exp2f(-1.44269504089f * x);
  return x * __builtin_amdgcn_rcpf(1.f + e);
}

// ---- setup: weight transpose+cvt, w256 pack, hist, zero m_i/pos_sum --------
__global__ void setup_kernel(const float* __restrict__ eW1, const float* __restrict__ eW2,
                             const float* __restrict__ cW1, const float* __restrict__ nW1,
                             const float* __restrict__ nW2, const int* __restrict__ ei,
                             ushort_t* __restrict__ eW1t, ushort_t* __restrict__ eW2t,
                             ushort_t* __restrict__ cW1t, ushort_t* __restrict__ nW1t,
                             ushort_t* __restrict__ nW2t, uint32_t* __restrict__ w256b,
                             int* __restrict__ hist, float4* __restrict__ zbase){
  int idx = blockIdx.x * 256 + threadIdx.x;
  if (idx < 32768){                      // eW1t[n*256+k] = eW1[k*128+n], k<256
    int n = idx >> 8, k = idx & 255;
    eW1t[idx] = f2bf(eW1[k * H + n]);
  } else if (idx < 49152){
    int j = idx - 32768; int n = j >> 7, k = j & 127;
    eW2t[j] = f2bf(eW2[k * H + n]);
  } else if (idx < 65536){
    int j = idx - 49152; int n = j >> 7, k = j & 127;
    cW1t[j] = f2bf(cW1[k * H + n]);
  } else if (idx < 98304){
    int j = idx - 65536; int n = j >> 8, k = j & 255;
    nW1t[j] = f2bf(nW1[k * H + n]);
  } else if (idx < 114688){
    int j = idx - 98304; int n = j >> 7, k = j & 127;
    nW2t[j] = f2bf(nW2[k * H + n]);
  } else if (idx < 114752){              // w256 packed bf16x2 (row 256 of eW1)
    int j = idx - 114688;
    w256b[j] = pk2bf(eW1[256 * H + 2*j], eW1[256 * H + 2*j + 1]);
  } else if (idx < 754752){              // degree histogram
    int j = idx - 114752;
    atomicAdd(&hist[ei[j]], 1);
  } else {                               // zero m_i + pos_sum (655000 float4s)
    int j = idx - 754752;
    if (j < 655000) zbase[j] = make_float4(0.f, 0.f, 0.f, 0.f);
  }
}

// ---- single-block exclusive scan: 1024 threads x 20 elements ---------------
__global__ void scan_kernel(const int* __restrict__ hist, int* __restrict__ head){
  __shared__ int s[1024];
  const int t = threadIdx.x;
  const int base = t * 20;
  int loc[20];
  int sum = 0;
  #pragma unroll
  for (int i = 0; i < 20; i++){
    int idx = base + i;
    int v = (idx < NNODES) ? hist[idx] : 0;
    loc[i] = sum;
    sum += v;
  }
  s[t] = sum;
  __syncthreads();
  for (int off = 1; off < 1024; off <<= 1){
    int tmp = (t >= off) ? s[t - off] : 0;
    __syncthreads();
    s[t] += tmp;
    __syncthreads();
  }
  int offv = s[t] - sum;                 // exclusive across threads
  #pragma unroll
  for (int i = 0; i < 20; i++){
    int idx = base + i;
    if (idx < NNODES) head[idx] = offv + loc[i];
  }
}

// ---- fused: P/Q/R precompute (blocks < PQ_BLOCKS) + CSR scatter (rest) -----
__global__ void pqscatter_kernel(const float* __restrict__ h,
                                 const ushort_t* __restrict__ eW1t,
                                 const ushort_t* __restrict__ nW1t,
                                 const float* __restrict__ eb1,
                                 ushort_t* __restrict__ Pb, ushort_t* __restrict__ Qb,
                                 ushort_t* __restrict__ Rb,
                                 const int* __restrict__ ei, int* __restrict__ head,
                                 int2* __restrict__ spair){
  if (blockIdx.x >= PQ_BLOCKS){          // ---- scatter part
    int idx = (blockIdx.x - PQ_BLOCKS) * 256 + threadIdx.x;
    if (idx < NEDGES){
      int r = ei[idx], c = ei[NEDGES + idx];
      int p = atomicAdd(&head[r], 1);
      spair[p] = make_int2(r, c);
    }
    return;
  }
  // ---- pq part
  const int t = threadIdx.x;
  const int lane = t & 63, q = lane >> 4, ln = lane & 15;
  const int nb = (t >> 6) * 32;
  const int c0 = nb + 2 * ln;
  const int base = blockIdx.x * 64;

  floatx4 accP[4][2], accQ[4][2], accR[4][2];
  #pragma unroll
  for (int mt = 0; mt < 4; mt++)
    #pragma unroll
    for (int nt = 0; nt < 2; nt++){
      accP[mt][nt] = (floatx4)0.f; accQ[mt][nt] = (floatx4)0.f; accR[mt][nt] = (floatx4)0.f;
    }

  #pragma unroll
  for (int ks = 0; ks < 4; ks++){
    short8 a[4];
    #pragma unroll
    for (int mt = 0; mt < 4; mt++){
      int node = base + mt*16 + ln;
      if (node >= NNODES) node = NNODES - 1;
      const float* hp = h + (size_t)node * H + ks*32 + q*8;
      float4 v0 = *(const float4*)hp;
      float4 v1 = *(const float4*)(hp + 4);
      uint32_t tw[4];
      tw[0] = pk2bf(v0.x, v0.y); tw[1] = pk2bf(v0.z, v0.w);
      tw[2] = pk2bf(v1.x, v1.y); tw[3] = pk2bf(v1.z, v1.w);
      __builtin_memcpy(&a[mt], tw, 16);
    }
    short8 bP[2], bQ[2], bR[2];
    #pragma unroll
    for (int nt = 0; nt < 2; nt++){
      bP[nt] = *(const short8*)(eW1t + (size_t)(c0 + nt) * 256 + ks*32 + q*8);
      bQ[nt] = *(const short8*)(eW1t + (size_t)(c0 + nt) * 256 + 128 + ks*32 + q*8);
      bR[nt] = *(const short8*)(nW1t + (size_t)(c0 + nt) * 256 + ks*32 + q*8);
    }
    #pragma unroll
    for (int mt = 0; mt < 4; mt++)
      #pragma unroll
      for (int nt = 0; nt < 2; nt++){
        accP[mt][nt] = __builtin_amdgcn_mfma_f32_16x16x32_bf16(a[mt], bP[nt], accP[mt][nt], 0, 0, 0);
        accQ[mt][nt] = __builtin_amdgcn_mfma_f32_16x16x32_bf16(a[mt], bQ[nt], accQ[mt][nt], 0, 0, 0);
        accR[mt][nt] = __builtin_amdgcn_mfma_f32_16x16x32_bf16(a[mt], bR[nt], accR[mt][nt], 0, 0, 0);
      }
  }
  float2 e1 = *(const float2*)(eb1 + c0);
  #pragma unroll
  for (int mt = 0; mt < 4; mt++)
    #pragma unroll
    for (int r = 0; r < 4; r++){
      int node = base + mt*16 + q*4 + r;
      if (node < NNODES){
        *(uint32_t*)(Pb + (size_t)node * H + c0) = pk2bf(accP[mt][0][r] + e1.x, accP[mt][1][r] + e1.y);
        *(uint32_t*)(Qb + (size_t)node * H + c0) = pk2bf(accQ[mt][0][r], accQ[mt][1][r]);
        *(uint32_t*)(Rb + (size_t)node * H + c0) = pk2bf(accR[mt][0][r], accR[mt][1][r]);
      }
    }
}

// ---------------- edge kernel + fused node tail -----------------------------
__global__ __launch_bounds__(256, 8) void edge_kernel(
    const ushort_t* __restrict__ Pb, const ushort_t* __restrict__ Qb,
    const float* __restrict__ pos, const int2* __restrict__ spair,
    const uint32_t* __restrict__ w256b,
    const float* __restrict__ eb2, const float* __restrict__ cb1,
    const float* __restrict__ cW2,
    const ushort_t* __restrict__ eW2t, const ushort_t* __restrict__ cW1t,
    float* __restrict__ m_i, float* __restrict__ pos_sum,
    // node-tail params
    const float* __restrict__ h, const float* __restrict__ nb1,
    const float* __restrict__ nb2, const ushort_t* __restrict__ nW1t,
    const ushort_t* __restrict__ nW2t, const ushort_t* __restrict__ Rb,
    const int* __restrict__ hist, int* __restrict__ cnt,
    float* __restrict__ h_out, float* __restrict__ pos_out)
{
  __shared__ __align__(16) ushort_t buf[TILE * 136];   // t1, then m_ij, then node t1
  __shared__ int   row_l[TILE];
  __shared__ float sq_l[TILE];
  __shared__ float dx_l[TILE], dy_l[TILE], dz_l[TILE];
  __shared__ float wbuf[TILE][4];
  __shared__ int   ticket_s;

  const int t = threadIdx.x;
  const int base = blockIdx.x * TILE;
  const int w = t >> 6;
  const int lane = t & 63, q = lane >> 4, ln = lane & 15;
  const int nb = w * 32;
  const int c0 = nb + 2 * ln;

  // ---- t1 build + staging: thread (i,p) handles 32 cols of edge i
  {
    const int i = t >> 2, p = t & 3;
    int2 rc = spair[base + i];
    float ax = pos[rc.x*3+0] - pos[rc.y*3+0];
    float ay = pos[rc.x*3+1] - pos[rc.y*3+1];
    float az = pos[rc.x*3+2] - pos[rc.y*3+2];
    float sq = ax*ax + ay*ay + az*az;
    if (p == 0){
      row_l[i] = rc.x; sq_l[i] = sq;
      dx_l[i] = ax; dy_l[i] = ay; dz_l[i] = az;
    }
    floatx2 sq2; sq2.x = sq; sq2.y = sq;
    const uint4* Pp = (const uint4*)(Pb + (size_t)rc.x * H + p*32);
    const uint4* Qp = (const uint4*)(Qb + (size_t)rc.y * H + p*32);
    const uint4* Wp = (const uint4*)(w256b + p*16);
    ushort_t* dst = buf + i * 136 + p*32;
    #pragma unroll
    for (int j = 0; j < 4; j++){
      uint4 pv = Pp[j], qv = Qp[j], wv = Wp[j];
      uint32_t pvv[4] = {pv.x, pv.y, pv.z, pv.w};
      uint32_t qvv[4] = {qv.x, qv.y, qv.z, qv.w};
      uint32_t wvv[4] = {wv.x, wv.y, wv.z, wv.w};
      uint32_t outv[4];
      #pragma unroll
      for (int e = 0; e < 4; e++){
        floatx2 f = bfpair2(pvv[e]) + bfpair2(qvv[e]) + sq2 * bfpair2(wvv[e]);
        outv[e] = pk2bf(silu_f(f.x), silu_f(f.y));
      }
      uint4 out; __builtin_memcpy(&out, outv, 16);
      *(uint4*)(dst + j*8) = out;
    }
  }
  __syncthreads();

  floatx4 acc[4][2];

  // ---- GEMM2: t1 @ eW2t -> m_ij
  #pragma unroll
  for (int mt = 0; mt < 4; mt++)
    #pragma unroll
    for (int nt = 0; nt < 2; nt++) acc[mt][nt] = (floatx4)0.f;
  #pragma unroll
  for (int ks = 0; ks < 4; ks++){
    short8 a[4], b[2];
    #pragma unroll
    for (int mt = 0; mt < 4; mt++)
      a[mt] = *(const short8*)(buf + (mt*16 + ln) * 136 + ks*32 + q*8);
    #pragma unroll
    for (int nt = 0; nt < 2; nt++)
      b[nt] = *(const short8*)(eW2t + (size_t)(c0 + nt) * 128 + ks*32 + q*8);
    #pragma unroll
    for (int mt = 0; mt < 4; mt++)
      #pragma unroll
      for (int nt = 0; nt < 2; nt++)
        acc[mt][nt] = __builtin_amdgcn_mfma_f32_16x16x32_bf16(a[mt], b[nt], acc[mt][nt], 0, 0, 0);
  }
  __syncthreads();
  {
    float2 e2 = *(const float2*)(eb2 + c0);
    #pragma unroll
    for (int mt = 0; mt < 4; mt++)
      #pragma unroll
      for (int r = 0; r < 4; r++){
        int m = mt*16 + q*4 + r;
        float f0 = silu_f(acc[mt][0][r] + e2.x);
        float f1 = silu_f(acc[mt][1][r] + e2.y);
        *(uint32_t*)(buf + m * 136 + c0) = pk2bf(f0, f1);
      }
  }
  __syncthreads();

  // ---- GEMM3: m_ij @ cW1t ; dot with cW2 -> per-edge scalar weight
  #pragma unroll
  for (int mt = 0; mt < 4; mt++)
    #pragma unroll
    for (int nt = 0; nt < 2; nt++) acc[mt][nt] = (floatx4)0.f;
  #pragma unroll
  for (int ks = 0; ks < 4; ks++){
    short8 a[4], b[2];
    #pragma unroll
    for (int mt = 0; mt < 4; mt++)
      a[mt] = *(const short8*)(buf + (mt*16 + ln) * 136 + ks*32 + q*8);
    #pragma unroll
    for (int nt = 0; nt < 2; nt++)
      b[nt] = *(const short8*)(cW1t + (size_t)(c0 + nt) * 128 + ks*32 + q*8);
    #pragma unroll
    for (int mt = 0; mt < 4; mt++)
      #pragma unroll
      for (int nt = 0; nt < 2; nt++)
        acc[mt][nt] = __builtin_amdgcn_mfma_f32_16x16x32_bf16(a[mt], b[nt], acc[mt][nt], 0, 0, 0);
  }
  {
    float2 c1 = *(const float2*)(cb1 + c0);
    float2 c2 = *(const float2*)(cW2 + c0);
    #pragma unroll
    for (int mt = 0; mt < 4; mt++)
      #pragma unroll
      for (int r = 0; r < 4; r++){
        float p = silu_f(acc[mt][0][r] + c1.x) * c2.x
                + silu_f(acc[mt][1][r] + c1.y) * c2.y;
        p += __shfl_xor(p, 1);
        p += __shfl_xor(p, 2);
        p += __shfl_xor(p, 4);
        p += __shfl_xor(p, 8);
        if (ln == 0) wbuf[mt*16 + q*4 + r][w] = p;
      }
  }
  __syncthreads();                                    // wbuf + buf(m_ij) ready

  // ---- segmented reduce m_ij -> m_i; 2 groups x 32 edges x 64 col-pairs
  if (t < 128){
    int cp = (t & 63) * 2;
    int ms = (t >> 6) * 32;
    float a0 = 0.f, a1 = 0.f;
    int cur = row_l[ms];
    #pragma unroll 4
    for (int mm = 0; mm < 32; mm++){
      int m = ms + mm;
      int rr = row_l[m];
      uint32_t v = *(const uint32_t*)(buf + m * 136 + cp);
      if (rr != cur){
        unsafeAtomicAdd(&m_i[(size_t)cur * H + cp],     a0);
        unsafeAtomicAdd(&m_i[(size_t)cur * H + cp + 1], a1);
        a0 = 0.f; a1 = 0.f; cur = rr;
      }
      floatx2 f = bfpair2(v);
      a0 += f.x; a1 += f.y;
    }
    unsafeAtomicAdd(&m_i[(size_t)cur * H + cp],     a0);
    unsafeAtomicAdd(&m_i[(size_t)cur * H + cp + 1], a1);
  } else if (t < 131){
    // ---- pos segmented reduce with inline scaling (3 threads, pre-combined)
    const int d = t - 128;
    const float* src = (d == 0) ? dx_l : (d == 1) ? dy_l : dz_l;
    float accv = 0.f;
    int cur = row_l[0];
    for (int m = 0; m < TILE; m++){
      int rr = row_l[m];
      if (rr != cur){
        unsafeAtomicAdd(&pos_sum[cur*3 + d], accv);
        accv = 0.f; cur = rr;
      }
      float wv = wbuf[m][0] + wbuf[m][1] + wbuf[m][2] + wbuf[m][3];
      float s = __builtin_amdgcn_rsqf(sq_l[m] + 1e-8f) * wv;
      accv += src[m] * s;
    }
    unsafeAtomicAdd(&pos_sum[cur*3 + d], accv);
  }

  // ======== node tail: last NODE_TILES finishers do one 32-node tile ========
  __threadfence();                                    // flush this block's atomics
  __syncthreads();
  if (t == 0) ticket_s = atomicAdd(cnt, 1);
  __syncthreads();
  const int ticket = ticket_s;
  if (ticket < EDGE_BLOCKS - NODE_TILES) return;

  if (t == 0){
    while (atomicAdd(cnt, 0) < EDGE_BLOCKS) __builtin_amdgcn_s_sleep(8);
  }
  __syncthreads();
  __threadfence();                                    // acquire all m_i/pos_sum

  const int nbase = (ticket - (EDGE_BLOCKS - NODE_TILES)) * 32;

  if (t < 32){
    int node = nbase + t;
    float c = fmaxf((float)hist[node], 1.f);
    float invc = __builtin_amdgcn_rcpf(c);
    pos_out[node*3+0] = pos[node*3+0] + pos_sum[node*3+0] * invc;
    pos_out[node*3+1] = pos[node*3+1] + pos_sum[node*3+1] * invc;
    pos_out[node*3+2] = pos[node*3+2] + pos_sum[node*3+2] * invc;
  }

  floatx4 nacc[2][2];
  #pragma unroll
  for (int mt = 0; mt < 2; mt++)
    #pragma unroll
    for (int nt = 0; nt < 2; nt++) nacc[mt][nt] = (floatx4)0.f;
  #pragma unroll
  for (int ks = 0; ks < 4; ks++){
    short8 a[2], b[2];
    #pragma unroll
    for (int mt = 0; mt < 2; mt++){
      const float* mp = m_i + (size_t)(nbase + mt*16 + ln) * H + ks*32 + q*8;
      float4 v0 = *(const float4*)mp;
      float4 v1 = *(const float4*)(mp + 4);
      uint32_t tw[4];
      tw[0] = pk2bf(v0.x, v0.y); tw[1] = pk2bf(v0.z, v0.w);
      tw[2] = pk2bf(v1.x, v1.y); tw[3] = pk2bf(v1.z, v1.w);
      __builtin_memcpy(&a[mt], tw, 16);
    }
    #pragma unroll
    for (int nt = 0; nt < 2; nt++)
      b[nt] = *(const short8*)(nW1t + (size_t)(c0 + nt) * 256 + 128 + ks*32 + q*8);
    #pragma unroll
    for (int mt = 0; mt < 2; mt++)
      #pragma unroll
      for (int nt = 0; nt < 2; nt++)
        nacc[mt][nt] = __builtin_amdgcn_mfma_f32_16x16x32_bf16(a[mt], b[nt], nacc[mt][nt], 0, 0, 0);
  }
  {
    float2 b1 = *(const float2*)(nb1 + c0);
    #pragma unroll
    for (int mt = 0; mt < 2; mt++)
      #pragma unroll
      for (int r = 0; r < 4; r++){
        int m = mt*16 + q*4 + r;
        int node = nbase + m;
        floatx2 rf = bfpair2(*(const uint32_t*)(Rb + (size_t)node * H + c0));
        float f0 = silu_f(nacc[mt][0][r] + rf.x + b1.x);
        float f1 = silu_f(nacc[mt][1][r] + rf.y + b1.y);
        *(uint32_t*)(buf + m * 136 + c0) = pk2bf(f0, f1);
      }
  }
  __syncthreads();

  #pragma unroll
  for (int mt = 0; mt < 2; mt++)
    #pragma unroll
    for (int nt = 0; nt < 2; nt++) nacc[mt][nt] = (floatx4)0.f;
  #pragma unroll
  for (int ks = 0; ks < 4; ks++){
    short8 a[2], b[2];
    #pragma unroll
    for (int mt = 0; mt < 2; mt++)
      a[mt] = *(const short8*)(buf + (mt*16 + ln) * 136 + ks*32 + q*8);
    #pragma unroll
    for (int nt = 0; nt < 2; nt++)
      b[nt] = *(const short8*)(nW2t + (size_t)(c0 + nt) * 128 + ks*32 + q*8);
    #pragma unroll
    for (int mt = 0; mt < 2; mt++)
      #pragma unroll
      for (int nt = 0; nt < 2; nt++)
        nacc[mt][nt] = __builtin_amdgcn_mfma_f32_16x16x32_bf16(a[mt], b[nt], nacc[mt][nt], 0, 0, 0);
  }
  {
    float2 b2 = *(const float2*)(nb2 + c0);
    #pragma unroll
    for (int mt = 0; mt < 2; mt++)
      #pragma unroll
      for (int r = 0; r < 4; r++){
        int node = nbase + mt*16 + q*4 + r;
        const float2 hv = *(const float2*)(h + (size_t)node * H + c0);
        float2 o;
        o.x = hv.x + nacc[mt][0][r] + b2.x;
        o.y = hv.y + nacc[mt][1][r] + b2.y;
        *(float2*)(h_out + (size_t)node * H + c0) = o;
      }
  }
}

// ---------------- launch ----------------------------------------------------
extern "C" void kernel_launch(void* const* d_in, const int* in_sizes, int n_in,
                              void* d_out, int out_size, void* d_ws, size_t ws_size,
                              hipStream_t stream){
  const float* h   = (const float*)d_in[0];
  const float* pos = (const float*)d_in[1];
  const int*   ei  = (const int*)d_in[2];
  const float* eW1 = (const float*)d_in[3];
  const float* eb1 = (const float*)d_in[4];
  const float* eW2 = (const float*)d_in[5];
  const float* eb2 = (const float*)d_in[6];
  const float* cW1 = (const float*)d_in[7];
  const float* cb1 = (const float*)d_in[8];
  const float* cW2 = (const float*)d_in[9];
  const float* nW1 = (const float*)d_in[10];
  const float* nb1 = (const float*)d_in[11];
  const float* nW2 = (const float*)d_in[12];
  const float* nb2 = (const float*)d_in[13];

  char* ws = (char*)d_ws;
  float*    m_i     = (float*)   (ws);                 // 10,240,000 B
  float*    pos_sum = (float*)   (ws + 10240000);      //    240,000 B
  int*      hist    = (int*)     (ws + 10480000);      //     80,000 B
  int*      cnt     = (int*)     (ws + 10560000);      //          4 B
  int*      head    = (int*)     (ws + 10560256);      //     80,000 B
  int2*     spair   = (int2*)    (ws + 10644096);      //  5,120,000 B
  ushort_t* Pb      = (ushort_t*)(ws + 15764096);      //  5,120,000 B
  ushort_t* eW1t    = (ushort_t*)(ws + 20884096);      //     65,536 B
  ushort_t* eW2t    = (ushort_t*)(ws + 20949632);      //     32,768 B
  ushort_t* cW1t    = (ushort_t*)(ws + 20982400);      //     32,768 B
  ushort_t* nW1t    = (ushort_t*)(ws + 21015168);      //     65,536 B
  ushort_t* nW2t    = (ushort_t*)(ws + 21080704);      //     32,768 B
  ushort_t* Qb      = (ushort_t*)(ws + 21113472);      //  5,120,000 B
  ushort_t* Rb      = (ushort_t*)(ws + 26233472);      //  5,120,000 B
  uint32_t* w256b   = (uint32_t*)(ws + 31353472);      //        256 B (end ~31.35 MB)

  (void)hipMemsetAsync(hist, 0, 80004, stream);        // hist + cnt

  // threads: 114752 (weights+w256) + 640000 (hist) + 655000 (zero) = 1,409,752
  setup_kernel<<<5507, 256, 0, stream>>>(eW1, eW2, cW1, nW1, nW2, ei,
                                         eW1t, eW2t, cW1t, nW1t, nW2t, w256b, hist,
                                         (float4*)ws);
  scan_kernel<<<1, 1024, 0, stream>>>(hist, head);
  pqscatter_kernel<<<PQ_BLOCKS + (NEDGES + 255) / 256, 256, 0, stream>>>(
      h, eW1t, nW1t, eb1, Pb, Qb, Rb, ei, head, spair);

  float* h_out   = (float*)d_out;
  float* pos_out = h_out + (size_t)NNODES * H;
  edge_kernel<<<EDGE_BLOCKS, 256, 0, stream>>>(Pb, Qb, pos, spair, w256b,
                                               eb2, cb1, cW2, eW2t, cW1t,
                                               m_i, pos_sum,
                                               h, nb1, nb2, nW1t, nW2t, Rb,
                                               hist, cnt, h_out, pos_out);
}

// Round 17
// 343.222 us; speedup vs baseline: 4.0966x; 4.0966x over previous
//
#include <hip/hip_runtime.h>
#include <hip/hip_bf16.h>
#include <cstdint>

#define H 128
#define NNODES 20000
#define NEDGES 640000
#define TILE 64
#define SCAN_BLOCKS 20
#define PQ_BLOCKS 313

typedef unsigned short ushort_t;
typedef __attribute__((ext_vector_type(8))) short short8;
typedef __attribute__((ext_vector_type(4))) float floatx4;
typedef __attribute__((ext_vector_type(2))) float floatx2;

__device__ __forceinline__ ushort_t f2bf(float f){
  uint32_t u = __builtin_bit_cast(uint32_t, f);
  u += 0x7fffu + ((u >> 16) & 1u);           // RNE
  return (ushort_t)(u >> 16);
}
// packed RNE fp32x2 -> bf16x2 (v_cvt_pk_bf16_f32 on gfx950)
__device__ __forceinline__ uint32_t pk2bf(float lo, float hi){
  __hip_bfloat162 h2 = __float22bfloat162_rn(make_float2(lo, hi));
  uint32_t u;
  __builtin_memcpy(&u, &h2, 4);
  return u;
}
// unpack bf16x2 dword -> packed float2
__device__ __forceinline__ floatx2 bfpair2(uint32_t u){
  floatx2 r;
  r.x = __builtin_bit_cast(float, u << 16);
  r.y = __builtin_bit_cast(float, u & 0xffff0000u);
  return r;
}
__device__ __forceinline__ float bf2f(ushort_t s){
  uint32_t u = ((uint32_t)s) << 16;
  return __builtin_bit_cast(float, u);
}
// fast silu: v_exp_f32 + v_rcp_f32
__device__ __forceinline__ float silu_f(float x){
  float e = __builtin_amdgcn_exp2f(-1.44269504089f * x);
  return x * __builtin_amdgcn_rcpf(1.f + e);
}

// ---- setup: weight transpose+cvt, w256 pack, hist, zero m_i/pos_sum --------
__global__ void setup_kernel(const float* __restrict__ eW1, const float* __restrict__ eW2,
                             const float* __restrict__ cW1, const float* __restrict__ nW1,
                             const float* __restrict__ nW2, const int* __restrict__ ei,
                             ushort_t* __restrict__ eW1t, ushort_t* __restrict__ eW2t,
                             ushort_t* __restrict__ cW1t, ushort_t* __restrict__ nW1t,
                             ushort_t* __restrict__ nW2t, uint32_t* __restrict__ w256b,
                             int* __restrict__ hist, float4* __restrict__ zbase){
  int idx = blockIdx.x * 256 + threadIdx.x;
  if (idx < 32768){                      // eW1t[n*256+k] = eW1[k*128+n], k<256
    int n = idx >> 8, k = idx & 255;
    eW1t[idx] = f2bf(eW1[k * H + n]);
  } else if (idx < 49152){
    int j = idx - 32768; int n = j >> 7, k = j & 127;
    eW2t[j] = f2bf(eW2[k * H + n]);
  } else if (idx < 65536){
    int j = idx - 49152; int n = j >> 7, k = j & 127;
    cW1t[j] = f2bf(cW1[k * H + n]);
  } else if (idx < 98304){
    int j = idx - 65536; int n = j >> 8, k = j & 255;
    nW1t[j] = f2bf(nW1[k * H + n]);
  } else if (idx < 114688){
    int j = idx - 98304; int n = j >> 7, k = j & 127;
    nW2t[j] = f2bf(nW2[k * H + n]);
  } else if (idx < 114752){              // w256 packed bf16x2 (row 256 of eW1)
    int j = idx - 114688;
    w256b[j] = pk2bf(eW1[256 * H + 2*j], eW1[256 * H + 2*j + 1]);
  } else if (idx < 754752){              // degree histogram
    int j = idx - 114752;
    atomicAdd(&hist[ei[j]], 1);
  } else {                               // zero m_i + pos_sum (655000 float4s)
    int j = idx - 754752;
    if (j < 655000) zbase[j] = make_float4(0.f, 0.f, 0.f, 0.f);
  }
}

// ---------------- CSR build: two-kernel scan (R10, known-good) --------------
__global__ void scanA_kernel(const int* __restrict__ hist, int* __restrict__ head,
                             int* __restrict__ totals){
  __shared__ int s[1024];
  const int t = threadIdx.x;
  const int idx = blockIdx.x * 1024 + t;
  int v = (idx < NNODES) ? hist[idx] : 0;
  s[t] = v;
  __syncthreads();
  for (int off = 1; off < 1024; off <<= 1){
    int tmp = (t >= off) ? s[t - off] : 0;
    __syncthreads();
    s[t] += tmp;
    __syncthreads();
  }
  if (idx < NNODES) head[idx] = s[t] - v;          // exclusive within block
  if (t == 1023) totals[blockIdx.x] = s[t];
}

__global__ void scanC_kernel(const int* __restrict__ totals, int* __restrict__ head){
  __shared__ int off_s;
  if (threadIdx.x == 0){
    int a = 0;
    for (int i = 0; i < (int)blockIdx.x; i++) a += totals[i];
    off_s = a;
  }
  __syncthreads();
  int idx = blockIdx.x * 1024 + threadIdx.x;
  if (idx < NNODES) head[idx] += off_s;
}

// ---- fused: P/Q/R precompute (blocks < PQ_BLOCKS) + CSR scatter (rest) -----
__global__ void pqscatter_kernel(const float* __restrict__ h,
                                 const ushort_t* __restrict__ eW1t,
                                 const ushort_t* __restrict__ nW1t,
                                 const float* __restrict__ eb1,
                                 ushort_t* __restrict__ Pb, ushort_t* __restrict__ Qb,
                                 ushort_t* __restrict__ Rb,
                                 const int* __restrict__ ei, int* __restrict__ head,
                                 int2* __restrict__ spair){
  if (blockIdx.x >= PQ_BLOCKS){          // ---- scatter part
    int idx = (blockIdx.x - PQ_BLOCKS) * 256 + threadIdx.x;
    if (idx < NEDGES){
      int r = ei[idx], c = ei[NEDGES + idx];
      int p = atomicAdd(&head[r], 1);
      spair[p] = make_int2(r, c);
    }
    return;
  }
  // ---- pq part
  const int t = threadIdx.x;
  const int lane = t & 63, q = lane >> 4, ln = lane & 15;
  const int nb = (t >> 6) * 32;
  const int c0 = nb + 2 * ln;
  const int base = blockIdx.x * 64;

  floatx4 accP[4][2], accQ[4][2], accR[4][2];
  #pragma unroll
  for (int mt = 0; mt < 4; mt++)
    #pragma unroll
    for (int nt = 0; nt < 2; nt++){
      accP[mt][nt] = (floatx4)0.f; accQ[mt][nt] = (floatx4)0.f; accR[mt][nt] = (floatx4)0.f;
    }

  #pragma unroll
  for (int ks = 0; ks < 4; ks++){
    short8 a[4];
    #pragma unroll
    for (int mt = 0; mt < 4; mt++){
      int node = base + mt*16 + ln;
      if (node >= NNODES) node = NNODES - 1;
      const float* hp = h + (size_t)node * H + ks*32 + q*8;
      float4 v0 = *(const float4*)hp;
      float4 v1 = *(const float4*)(hp + 4);
      uint32_t tw[4];
      tw[0] = pk2bf(v0.x, v0.y); tw[1] = pk2bf(v0.z, v0.w);
      tw[2] = pk2bf(v1.x, v1.y); tw[3] = pk2bf(v1.z, v1.w);
      __builtin_memcpy(&a[mt], tw, 16);
    }
    short8 bP[2], bQ[2], bR[2];
    #pragma unroll
    for (int nt = 0; nt < 2; nt++){
      bP[nt] = *(const short8*)(eW1t + (size_t)(c0 + nt) * 256 + ks*32 + q*8);
      bQ[nt] = *(const short8*)(eW1t + (size_t)(c0 + nt) * 256 + 128 + ks*32 + q*8);
      bR[nt] = *(const short8*)(nW1t + (size_t)(c0 + nt) * 256 + ks*32 + q*8);
    }
    #pragma unroll
    for (int mt = 0; mt < 4; mt++)
      #pragma unroll
      for (int nt = 0; nt < 2; nt++){
        accP[mt][nt] = __builtin_amdgcn_mfma_f32_16x16x32_bf16(a[mt], bP[nt], accP[mt][nt], 0, 0, 0);
        accQ[mt][nt] = __builtin_amdgcn_mfma_f32_16x16x32_bf16(a[mt], bQ[nt], accQ[mt][nt], 0, 0, 0);
        accR[mt][nt] = __builtin_amdgcn_mfma_f32_16x16x32_bf16(a[mt], bR[nt], accR[mt][nt], 0, 0, 0);
      }
  }
  float2 e1 = *(const float2*)(eb1 + c0);
  #pragma unroll
  for (int mt = 0; mt < 4; mt++)
    #pragma unroll
    for (int r = 0; r < 4; r++){
      int node = base + mt*16 + q*4 + r;
      if (node < NNODES){
        *(uint32_t*)(Pb + (size_t)node * H + c0) = pk2bf(accP[mt][0][r] + e1.x, accP[mt][1][r] + e1.y);
        *(uint32_t*)(Qb + (size_t)node * H + c0) = pk2bf(accQ[mt][0][r], accQ[mt][1][r]);
        *(uint32_t*)(Rb + (size_t)node * H + c0) = pk2bf(accR[mt][0][r], accR[mt][1][r]);
      }
    }
}

// ---------------- edge kernel (R11/R13, best measured) ----------------------
__global__ __launch_bounds__(256, 8) void edge_kernel(
    const ushort_t* __restrict__ Pb, const ushort_t* __restrict__ Qb,
    const float* __restrict__ pos, const int2* __restrict__ spair,
    const uint32_t* __restrict__ w256b,
    const float* __restrict__ eb2, const float* __restrict__ cb1,
    const float* __restrict__ cW2,
    const ushort_t* __restrict__ eW2t, const ushort_t* __restrict__ cW1t,
    float* __restrict__ m_i, float* __restrict__ pos_sum)
{
  __shared__ __align__(16) ushort_t buf[TILE * 136];   // t1, then m_ij
  __shared__ int   row_l[TILE];
  __shared__ float sq_l[TILE];
  __shared__ float dx_l[TILE], dy_l[TILE], dz_l[TILE], w_l[TILE];

  const int t = threadIdx.x;
  const int base = blockIdx.x * TILE;
  const int lane = t & 63, q = lane >> 4, ln = lane & 15;
  const int nb = (t >> 6) * 32;
  const int c0 = nb + 2 * ln;

  // ---- t1 build + staging: thread (i,p) handles 32 cols of edge i
  {
    const int i = t >> 2, p = t & 3;
    int2 rc = spair[base + i];
    float ax = pos[rc.x*3+0] - pos[rc.y*3+0];
    float ay = pos[rc.x*3+1] - pos[rc.y*3+1];
    float az = pos[rc.x*3+2] - pos[rc.y*3+2];
    float sq = ax*ax + ay*ay + az*az;
    if (p == 0){
      row_l[i] = rc.x; sq_l[i] = sq;
      dx_l[i] = ax; dy_l[i] = ay; dz_l[i] = az;
      w_l[i] = 0.f;
    }
    floatx2 sq2; sq2.x = sq; sq2.y = sq;
    const uint4* Pp = (const uint4*)(Pb + (size_t)rc.x * H + p*32);
    const uint4* Qp = (const uint4*)(Qb + (size_t)rc.y * H + p*32);
    const uint4* Wp = (const uint4*)(w256b + p*16);
    ushort_t* dst = buf + i * 136 + p*32;
    #pragma unroll
    for (int j = 0; j < 4; j++){
      uint4 pv = Pp[j], qv = Qp[j], wv = Wp[j];
      uint32_t pvv[4] = {pv.x, pv.y, pv.z, pv.w};
      uint32_t qvv[4] = {qv.x, qv.y, qv.z, qv.w};
      uint32_t wvv[4] = {wv.x, wv.y, wv.z, wv.w};
      uint32_t outv[4];
      #pragma unroll
      for (int e = 0; e < 4; e++){
        floatx2 f = bfpair2(pvv[e]) + bfpair2(qvv[e]) + sq2 * bfpair2(wvv[e]);
        outv[e] = pk2bf(silu_f(f.x), silu_f(f.y));
      }
      uint4 out; __builtin_memcpy(&out, outv, 16);
      *(uint4*)(dst + j*8) = out;
    }
  }
  __syncthreads();

  floatx4 acc[4][2];

  // ---- GEMM2: t1 @ eW2t -> m_ij
  #pragma unroll
  for (int mt = 0; mt < 4; mt++)
    #pragma unroll
    for (int nt = 0; nt < 2; nt++) acc[mt][nt] = (floatx4)0.f;
  #pragma unroll
  for (int ks = 0; ks < 4; ks++){
    short8 a[4], b[2];
    #pragma unroll
    for (int mt = 0; mt < 4; mt++)
      a[mt] = *(const short8*)(buf + (mt*16 + ln) * 136 + ks*32 + q*8);
    #pragma unroll
    for (int nt = 0; nt < 2; nt++)
      b[nt] = *(const short8*)(eW2t + (size_t)(c0 + nt) * 128 + ks*32 + q*8);
    #pragma unroll
    for (int mt = 0; mt < 4; mt++)
      #pragma unroll
      for (int nt = 0; nt < 2; nt++)
        acc[mt][nt] = __builtin_amdgcn_mfma_f32_16x16x32_bf16(a[mt], b[nt], acc[mt][nt], 0, 0, 0);
  }
  __syncthreads();
  {
    float2 e2 = *(const float2*)(eb2 + c0);
    #pragma unroll
    for (int mt = 0; mt < 4; mt++)
      #pragma unroll
      for (int r = 0; r < 4; r++){
        int m = mt*16 + q*4 + r;
        float f0 = silu_f(acc[mt][0][r] + e2.x);
        float f1 = silu_f(acc[mt][1][r] + e2.y);
        *(uint32_t*)(buf + m * 136 + c0) = pk2bf(f0, f1);
      }
  }
  __syncthreads();

  // ---- GEMM3: m_ij @ cW1t ; dot with cW2 -> per-edge scalar weight
  #pragma unroll
  for (int mt = 0; mt < 4; mt++)
    #pragma unroll
    for (int nt = 0; nt < 2; nt++) acc[mt][nt] = (floatx4)0.f;
  #pragma unroll
  for (int ks = 0; ks < 4; ks++){
    short8 a[4], b[2];
    #pragma unroll
    for (int mt = 0; mt < 4; mt++)
      a[mt] = *(const short8*)(buf + (mt*16 + ln) * 136 + ks*32 + q*8);
    #pragma unroll
    for (int nt = 0; nt < 2; nt++)
      b[nt] = *(const short8*)(cW1t + (size_t)(c0 + nt) * 128 + ks*32 + q*8);
    #pragma unroll
    for (int mt = 0; mt < 4; mt++)
      #pragma unroll
      for (int nt = 0; nt < 2; nt++)
        acc[mt][nt] = __builtin_amdgcn_mfma_f32_16x16x32_bf16(a[mt], b[nt], acc[mt][nt], 0, 0, 0);
  }
  {
    float2 c1 = *(const float2*)(cb1 + c0);
    float2 c2 = *(const float2*)(cW2 + c0);
    #pragma unroll
    for (int mt = 0; mt < 4; mt++)
      #pragma unroll
      for (int r = 0; r < 4; r++){
        float p = silu_f(acc[mt][0][r] + c1.x) * c2.x
                + silu_f(acc[mt][1][r] + c1.y) * c2.y;
        p += __shfl_xor(p, 1);
        p += __shfl_xor(p, 2);
        p += __shfl_xor(p, 4);
        p += __shfl_xor(p, 8);
        if (ln == 0) atomicAdd(&w_l[mt*16 + q*4 + r], p);
      }
  }
  __syncthreads();                                  // w_l ready, buf=m_ij

  // ---- segmented reduce m_ij -> m_i; 2 groups x 32 edges x 64 col-pairs
  if (t < 128){
    int cp = (t & 63) * 2;
    int ms = (t >> 6) * 32;
    float a0 = 0.f, a1 = 0.f;
    int cur = row_l[ms];
    #pragma unroll 4
    for (int mm = 0; mm < 32; mm++){
      int m = ms + mm;
      int rr = row_l[m];
      uint32_t v = *(const uint32_t*)(buf + m * 136 + cp);
      if (rr != cur){
        unsafeAtomicAdd(&m_i[(size_t)cur * H + cp],     a0);
        unsafeAtomicAdd(&m_i[(size_t)cur * H + cp + 1], a1);
        a0 = 0.f; a1 = 0.f; cur = rr;
      }
      floatx2 f = bfpair2(v);
      a0 += f.x; a1 += f.y;
    }
    unsafeAtomicAdd(&m_i[(size_t)cur * H + cp],     a0);
    unsafeAtomicAdd(&m_i[(size_t)cur * H + cp + 1], a1);
  } else if (t < 131){
    // ---- pos segmented reduce with inline scaling (3 threads)
    const int d = t - 128;
    const float* src = (d == 0) ? dx_l : (d == 1) ? dy_l : dz_l;
    float accv = 0.f;
    int cur = row_l[0];
    for (int m = 0; m < TILE; m++){
      int rr = row_l[m];
      if (rr != cur){
        unsafeAtomicAdd(&pos_sum[cur*3 + d], accv);
        accv = 0.f; cur = rr;
      }
      float s = __builtin_amdgcn_rsqf(sq_l[m] + 1e-8f) * w_l[m];
      accv += src[m] * s;
    }
    unsafeAtomicAdd(&pos_sum[cur*3 + d], accv);
  }
}

// ---------------- node kernel: 32 nodes/block, 625 blocks -------------------
__global__ __launch_bounds__(256, 8) void node_kernel(
    const float* __restrict__ h, const float* __restrict__ pos,
    const float* __restrict__ nb1, const float* __restrict__ nb2,
    const ushort_t* __restrict__ nW1t, const ushort_t* __restrict__ nW2t,
    const ushort_t* __restrict__ Rb,
    const float* __restrict__ m_i, const float* __restrict__ pos_sum,
    const int* __restrict__ hist,
    float* __restrict__ h_out, float* __restrict__ pos_out)
{
  __shared__ __align__(16) ushort_t bufT[32 * 136];
  const int t = threadIdx.x;
  const int base = blockIdx.x * 32;
  const int lane = t & 63, q = lane >> 4, ln = lane & 15;
  const int nb_ = (t >> 6) * 32;
  const int c0 = nb_ + 2 * ln;

  if (t < 32){
    int node = base + t;
    float c = fmaxf((float)hist[node], 1.f);
    float invc = __builtin_amdgcn_rcpf(c);
    pos_out[node*3+0] = pos[node*3+0] + pos_sum[node*3+0] * invc;
    pos_out[node*3+1] = pos[node*3+1] + pos_sum[node*3+1] * invc;
    pos_out[node*3+2] = pos[node*3+2] + pos_sum[node*3+2] * invc;
  }

  floatx4 acc[2][2];
  #pragma unroll
  for (int mt = 0; mt < 2; mt++)
    #pragma unroll
    for (int nt = 0; nt < 2; nt++) acc[mt][nt] = (floatx4)0.f;
  #pragma unroll
  for (int ks = 0; ks < 4; ks++){
    short8 a[2], b[2];
    #pragma unroll
    for (int mt = 0; mt < 2; mt++){
      const float* mp = m_i + (size_t)(base + mt*16 + ln) * H + ks*32 + q*8;
      float4 v0 = *(const float4*)mp;
      float4 v1 = *(const float4*)(mp + 4);
      uint32_t tw[4];
      tw[0] = pk2bf(v0.x, v0.y); tw[1] = pk2bf(v0.z, v0.w);
      tw[2] = pk2bf(v1.x, v1.y); tw[3] = pk2bf(v1.z, v1.w);
      __builtin_memcpy(&a[mt], tw, 16);
    }
    #pragma unroll
    for (int nt = 0; nt < 2; nt++)
      b[nt] = *(const short8*)(nW1t + (size_t)(c0 + nt) * 256 + 128 + ks*32 + q*8);
    #pragma unroll
    for (int mt = 0; mt < 2; mt++)
      #pragma unroll
      for (int nt = 0; nt < 2; nt++)
        acc[mt][nt] = __builtin_amdgcn_mfma_f32_16x16x32_bf16(a[mt], b[nt], acc[mt][nt], 0, 0, 0);
  }
  {
    float2 b1 = *(const float2*)(nb1 + c0);
    #pragma unroll
    for (int mt = 0; mt < 2; mt++)
      #pragma unroll
      for (int r = 0; r < 4; r++){
        int m = mt*16 + q*4 + r;
        int node = base + m;
        floatx2 rf = bfpair2(*(const uint32_t*)(Rb + (size_t)node * H + c0));
        float f0 = silu_f(acc[mt][0][r] + rf.x + b1.x);
        float f1 = silu_f(acc[mt][1][r] + rf.y + b1.y);
        *(uint32_t*)(bufT + m * 136 + c0) = pk2bf(f0, f1);
      }
  }
  __syncthreads();

  #pragma unroll
  for (int mt = 0; mt < 2; mt++)
    #pragma unroll
    for (int nt = 0; nt < 2; nt++) acc[mt][nt] = (floatx4)0.f;
  #pragma unroll
  for (int ks = 0; ks < 4; ks++){
    short8 a[2], b[2];
    #pragma unroll
    for (int mt = 0; mt < 2; mt++)
      a[mt] = *(const short8*)(bufT + (mt*16 + ln) * 136 + ks*32 + q*8);
    #pragma unroll
    for (int nt = 0; nt < 2; nt++)
      b[nt] = *(const short8*)(nW2t + (size_t)(c0 + nt) * 128 + ks*32 + q*8);
    #pragma unroll
    for (int mt = 0; mt < 2; mt++)
      #pragma unroll
      for (int nt = 0; nt < 2; nt++)
        acc[mt][nt] = __builtin_amdgcn_mfma_f32_16x16x32_bf16(a[mt], b[nt], acc[mt][nt], 0, 0, 0);
  }
  {
    float2 b2 = *(const float2*)(nb2 + c0);
    #pragma unroll
    for (int mt = 0; mt < 2; mt++)
      #pragma unroll
      for (int r = 0; r < 4; r++){
        int node = base + mt*16 + q*4 + r;
        const float2 hv = *(const float2*)(h + (size_t)node * H + c0);
        float2 o;
        o.x = hv.x + acc[mt][0][r] + b2.x;
        o.y = hv.y + acc[mt][1][r] + b2.y;
        *(float2*)(h_out + (size_t)node * H + c0) = o;
      }
  }
}

// ---------------- launch ----------------------------------------------------
extern "C" void kernel_launch(void* const* d_in, const int* in_sizes, int n_in,
                              void* d_out, int out_size, void* d_ws, size_t ws_size,
                              hipStream_t stream){
  const float* h   = (const float*)d_in[0];
  const float* pos = (const float*)d_in[1];
  const int*   ei  = (const int*)d_in[2];
  const float* eW1 = (const float*)d_in[3];
  const float* eb1 = (const float*)d_in[4];
  const float* eW2 = (const float*)d_in[5];
  const float* eb2 = (const float*)d_in[6];
  const float* cW1 = (const float*)d_in[7];
  const float* cb1 = (const float*)d_in[8];
  const float* cW2 = (const float*)d_in[9];
  const float* nW1 = (const float*)d_in[10];
  const float* nb1 = (const float*)d_in[11];
  const float* nW2 = (const float*)d_in[12];
  const float* nb2 = (const float*)d_in[13];

  char* ws = (char*)d_ws;
  float*    m_i     = (float*)   (ws);                 // 10,240,000 B
  float*    pos_sum = (float*)   (ws + 10240000);      //    240,000 B
  int*      hist    = (int*)     (ws + 10480000);      //     80,000 B
  int*      head    = (int*)     (ws + 10560000);      //     80,000 B
  int*      totals  = (int*)     (ws + 10640000);      //      2,048 B
  int2*     spair   = (int2*)    (ws + 10644096);      //  5,120,000 B
  ushort_t* Pb      = (ushort_t*)(ws + 15764096);      //  5,120,000 B
  ushort_t* eW1t    = (ushort_t*)(ws + 20884096);      //     65,536 B
  ushort_t* eW2t    = (ushort_t*)(ws + 20949632);      //     32,768 B
  ushort_t* cW1t    = (ushort_t*)(ws + 20982400);      //     32,768 B
  ushort_t* nW1t    = (ushort_t*)(ws + 21015168);      //     65,536 B
  ushort_t* nW2t    = (ushort_t*)(ws + 21080704);      //     32,768 B
  ushort_t* Qb      = (ushort_t*)(ws + 21113472);      //  5,120,000 B
  ushort_t* Rb      = (ushort_t*)(ws + 26233472);      //  5,120,000 B
  uint32_t* w256b   = (uint32_t*)(ws + 31353472);      //        256 B (end ~31.35 MB)

  (void)hipMemsetAsync(hist, 0, 80000, stream);        // hist only

  // threads: 114752 (weights+w256) + 640000 (hist) + 655000 (zero) = 1,409,752
  setup_kernel<<<5507, 256, 0, stream>>>(eW1, eW2, cW1, nW1, nW2, ei,
                                         eW1t, eW2t, cW1t, nW1t, nW2t, w256b, hist,
                                         (float4*)ws);
  scanA_kernel<<<SCAN_BLOCKS, 1024, 0, stream>>>(hist, head, totals);
  scanC_kernel<<<SCAN_BLOCKS, 1024, 0, stream>>>(totals, head);
  pqscatter_kernel<<<PQ_BLOCKS + (NEDGES + 255) / 256, 256, 0, stream>>>(
      h, eW1t, nW1t, eb1, Pb, Qb, Rb, ei, head, spair);

  edge_kernel<<<NEDGES / TILE, 256, 0, stream>>>(Pb, Qb, pos, spair, w256b,
                                                 eb2, cb1, cW2,
                                                 eW2t, cW1t, m_i, pos_sum);

  float* h_out   = (float*)d_out;
  float* pos_out = h_out + (size_t)NNODES * H;
  node_kernel<<<NNODES / 32, 256, 0, stream>>>(h, pos, nb1, nb2,
                                               nW1t, nW2t, Rb, m_i, pos_sum,
                                               hist, h_out, pos_out);
}